// Round 5
// baseline (291.312 us; speedup 1.0000x reference)
//
#include <hip/hip_runtime.h>

// Problem constants (match reference)
#define B_      16
#define L_      4096
#define D_      256
#define K2_     512     // 2*D
#define TILE_M  32      // rows per 1-wave workgroup tile
#define MAXT    128     // max tiles per batch (4096/32)
#define KITERS  8       // K2_/64
#define PSTRIDE 260     // floats per (b,tile) partial record: [m, sA, sO[256], pad]

typedef float f32x4 __attribute__((ext_vector_type(4)));
typedef short bf16x8 __attribute__((ext_vector_type(8)));

__device__ __forceinline__ unsigned short f2bf(float x) {
    unsigned int u = __float_as_uint(x);
    u += 0x7FFF + ((u >> 16) & 1);      // round-to-nearest-even
    return (unsigned short)(u >> 16);
}
__device__ __forceinline__ unsigned int pk2(float a, float b) {
    return (unsigned int)f2bf(a) | ((unsigned int)f2bf(b) << 16);
}
__device__ __forceinline__ bf16x8 pack8(f32x4 a, f32x4 b) {
    union { bf16x8 v; unsigned int u[4]; } r;
    r.u[0] = pk2(a[0], a[1]); r.u[1] = pk2(a[2], a[3]);
    r.u[2] = pk2(b[0], b[1]); r.u[3] = pk2(b[2], b[3]);
    return r.v;
}
__device__ __forceinline__ float fast_tanh(float x) {
    float e = __expf(2.0f * x);
    return 1.0f - __fdividef(2.0f, e + 1.0f);
}

// ---------------------------------------------------------------------------
// prep: blk<256: W_hist -> bf16 d-major copy (wsW[d*512+e]); blk 256..271: aeff;
//       blk 272: compacted valid-tile table (32-row tiles)
// ---------------------------------------------------------------------------
__global__ __launch_bounds__(256) void prep_kernel(
    const float* __restrict__ Wh, const float* __restrict__ protos,
    const float* __restrict__ q, const int* __restrict__ pidx,
    const int* __restrict__ lengths,
    unsigned int* __restrict__ wsW32, float* __restrict__ aeff,
    int* __restrict__ tiles, int* __restrict__ tileCnt)
{
    const int blk = blockIdx.x, tid = threadIdx.x;
    if (blk < 256) {
        int d = blk;
        int e = tid * 2;
        float2 w = *reinterpret_cast<const float2*>(Wh + d * K2_ + e);
        wsW32[d * 256 + tid] = pk2(w.x, w.y);
    } else if (blk < 272) {
        int b = blk - 256;
        int d = tid;
        int pi = pidx[0];
        aeff[b * D_ + d] = (protos[pi * D_ + d] + 0.5f * q[b * D_ + d]) * 0.0625f;
    } else {
        // compact valid (b,t) 32-row tile list
        int nT = 0;
        if (tid < B_) nT = min(MAXT, (lengths[tid] + TILE_M - 1) / TILE_M);
        int pre = 0, tot = 0;
#pragma unroll
        for (int j = 0; j < B_; ++j) {
            int v = __shfl(nT, j, 64);
            tot += v;
            if (j < tid) pre += v;
        }
        if (tid < B_) {
            for (int t = 0; t < nT; ++t) tiles[pre + t] = (tid << 16) | t;
        }
        if (tid == 0) tileCnt[0] = tot;
    }
}

// ---------------------------------------------------------------------------
// main: 1 wave per block; tile = 32 rows x 256 cols; NO LDS, NO barriers.
// A: direct f32 loads -> bf16 regs. B: direct loads from L2-resident bf16 ws.
// Epilogue softmax entirely within-wave via shuffles.
// ---------------------------------------------------------------------------
__global__ __launch_bounds__(64, 2) void main_kernel(
    const float* __restrict__ h, const float* __restrict__ rp, const float* __restrict__ rn,
    const int* __restrict__ lengths, const unsigned short* __restrict__ wsW,
    const float* __restrict__ aeff, const float* __restrict__ bhist,
    float* __restrict__ partials, const int* __restrict__ tiles,
    const int* __restrict__ tileCnt)
{
    const int bid = blockIdx.x;
    if (bid >= tileCnt[0]) return;
    const int ent = tiles[bid];
    const int b   = ent >> 16;
    const int t   = ent & 0xFFFF;
    const int len = lengths[b];
    const int l0  = t * TILE_M;

    const int lane = threadIdx.x & 63;
    const int r16  = lane & 15;
    const int kg   = lane >> 4;

    // A row pointers: lane covers row (l0 + mt*16 + r16), k-offset kg*8 within a 32-k step
    const size_t rowOff = ((size_t)(b * L_ + l0 + r16)) * D_ + kg * 8;
    const float* hRow  = h  + rowOff;
    const float* rpRow = rp + rowOff;
    const float* rnRow = rn + rowOff;
    // B base: col d = nt*16 + r16, k-chunk kg*8 (bytes: d*1024 + k*2)
    const char* uB = reinterpret_cast<const char*>(wsW) + r16 * 1024 + kg * 16;

    const f32x4 zero4 = {0.f, 0.f, 0.f, 0.f};
    f32x4 acc0[16], acc1[16];
#pragma unroll
    for (int nt = 0; nt < 16; ++nt) { acc0[nt] = zero4; acc1[nt] = zero4; }

    // ---- K-loop: h half (k 0..255) ----
#pragma unroll
    for (int tk = 0; tk < 4; ++tk) {
        bf16x8 frag[2][2];
#pragma unroll
        for (int mt = 0; mt < 2; ++mt)
#pragma unroll
            for (int ks = 0; ks < 2; ++ks) {
                const float* p = hRow + mt * 16 * D_ + tk * 64 + ks * 32;
                f32x4 v0 = *reinterpret_cast<const f32x4*>(p);
                f32x4 v1 = *reinterpret_cast<const f32x4*>(p + 4);
                frag[mt][ks] = pack8(v0, v1);
            }
#pragma unroll
        for (int ks = 0; ks < 2; ++ks)
#pragma unroll
            for (int nt = 0; nt < 16; ++nt) {
                bf16x8 bfr = *reinterpret_cast<const bf16x8*>(uB + nt * 16384 + tk * 128 + ks * 64);
                acc0[nt] = __builtin_amdgcn_mfma_f32_16x16x32_bf16(frag[0][ks], bfr, acc0[nt], 0, 0, 0);
                acc1[nt] = __builtin_amdgcn_mfma_f32_16x16x32_bf16(frag[1][ks], bfr, acc1[nt], 0, 0, 0);
            }
    }
    // ---- K-loop: (rp - rn) half (k 256..511) ----
#pragma unroll
    for (int tk = 4; tk < 8; ++tk) {
        bf16x8 frag[2][2];
#pragma unroll
        for (int mt = 0; mt < 2; ++mt)
#pragma unroll
            for (int ks = 0; ks < 2; ++ks) {
                const int off = mt * 16 * D_ + (tk - 4) * 64 + ks * 32;
                f32x4 p0 = *reinterpret_cast<const f32x4*>(rpRow + off);
                f32x4 p1 = *reinterpret_cast<const f32x4*>(rpRow + off + 4);
                f32x4 n0 = *reinterpret_cast<const f32x4*>(rnRow + off);
                f32x4 n1 = *reinterpret_cast<const f32x4*>(rnRow + off + 4);
                frag[mt][ks] = pack8(p0 - n0, p1 - n1);
            }
#pragma unroll
        for (int ks = 0; ks < 2; ++ks)
#pragma unroll
            for (int nt = 0; nt < 16; ++nt) {
                bf16x8 bfr = *reinterpret_cast<const bf16x8*>(uB + nt * 16384 + tk * 128 + ks * 64);
                acc0[nt] = __builtin_amdgcn_mfma_f32_16x16x32_bf16(frag[0][ks], bfr, acc0[nt], 0, 0, 0);
                acc1[nt] = __builtin_amdgcn_mfma_f32_16x16x32_bf16(frag[1][ks], bfr, acc1[nt], 0, 0, 0);
            }
    }

    // ---- epilogue: tanh, logits, within-wave softmax partials ----
    float av[16], bhv[16];
#pragma unroll
    for (int nt = 0; nt < 16; ++nt) {
        int col = nt * 16 + r16;
        av[nt]  = aeff[b * D_ + col];
        bhv[nt] = bhist[col];
    }
    float part0[4] = {0.f, 0.f, 0.f, 0.f};
    float part1[4] = {0.f, 0.f, 0.f, 0.f};
#pragma unroll
    for (int nt = 0; nt < 16; ++nt)
#pragma unroll
        for (int rgi = 0; rgi < 4; ++rgi) {
            float o0 = fast_tanh(acc0[nt][rgi] + bhv[nt]);
            float o1 = fast_tanh(acc1[nt][rgi] + bhv[nt]);
            acc0[nt][rgi] = o0;
            acc1[nt][rgi] = o1;
            part0[rgi] += o0 * av[nt];
            part1[rgi] += o1 * av[nt];
        }
    // reduce over the 16 col-lanes (r16): complete logits per (mt,kg,rgi)
#pragma unroll
    for (int off = 1; off < 16; off <<= 1)
#pragma unroll
        for (int rgi = 0; rgi < 4; ++rgi) {
            part0[rgi] += __shfl_xor(part0[rgi], off, 64);
            part1[rgi] += __shfl_xor(part1[rgi], off, 64);
        }
    // validity and wave max over 32 rows
    float mv = -3.0e38f;
    bool val0[4], val1[4];
#pragma unroll
    for (int rgi = 0; rgi < 4; ++rgi) {
        int row = kg * 4 + rgi;
        val0[rgi] = (l0 + row) < len;
        val1[rgi] = (l0 + 16 + row) < len;
        if (val0[rgi]) mv = fmaxf(mv, part0[rgi]);
        if (val1[rgi]) mv = fmaxf(mv, part1[rgi]);
    }
    mv = fmaxf(mv, __shfl_xor(mv, 16, 64));
    mv = fmaxf(mv, __shfl_xor(mv, 32, 64));
    // p and sum
    float p0[4], p1[4];
    float sa = 0.f;
#pragma unroll
    for (int rgi = 0; rgi < 4; ++rgi) {
        p0[rgi] = val0[rgi] ? __expf(part0[rgi] - mv) : 0.f;
        p1[rgi] = val1[rgi] ? __expf(part1[rgi] - mv) : 0.f;
        sa += p0[rgi] + p1[rgi];
    }
    sa += __shfl_xor(sa, 16, 64);
    sa += __shfl_xor(sa, 32, 64);

    float* pout = partials + (size_t)(b * MAXT + t) * PSTRIDE;
    // sO[col] = sum_rows p * o
#pragma unroll
    for (int nt = 0; nt < 16; ++nt) {
        float so = 0.f;
#pragma unroll
        for (int rgi = 0; rgi < 4; ++rgi)
            so += p0[rgi] * acc0[nt][rgi] + p1[rgi] * acc1[nt][rgi];
        so += __shfl_xor(so, 16, 64);
        so += __shfl_xor(so, 32, 64);
        if (kg == 0) pout[2 + nt * 16 + r16] = so;
    }
    if (lane == 0) { pout[0] = mv; pout[1] = sa; }
}

// ---------------------------------------------------------------------------
// sq_kernel: grid (16,4); block (b, cy) combines tile partials for 64 cols
// ---------------------------------------------------------------------------
__global__ __launch_bounds__(256) void sq_kernel(
    const float* __restrict__ partials, const int* __restrict__ lengths,
    float* __restrict__ sqout)
{
    const int b   = blockIdx.x;
    const int cy  = blockIdx.y;
    const int tid = threadIdx.x;
    const int c   = tid & 63;
    const int tg  = tid >> 6;
    const int len = lengths[b];
    const int nT  = min(MAXT, (len + TILE_M - 1) / TILE_M);

    __shared__ float mArr[MAXT];
    __shared__ float sAArr[MAXT];
    __shared__ float psum[4][64];

    const float* pbase = partials + (size_t)b * MAXT * PSTRIDE;
    if (tid < nT) {
        mArr[tid]  = pbase[(size_t)tid * PSTRIDE];
        sAArr[tid] = pbase[(size_t)tid * PSTRIDE + 1];
    }
    __syncthreads();

    float M = -3.0e38f;
    for (int t = 0; t < nT; ++t) M = fmaxf(M, mArr[t]);
    float den = 0.f;
    for (int t = 0; t < nT; ++t) den += __expf(mArr[t] - M) * sAArr[t];

    float num = 0.f;
    for (int t = tg; t < nT; t += 4)
        num += __expf(mArr[t] - M) * pbase[(size_t)t * PSTRIDE + 2 + cy * 64 + c];
    psum[tg][c] = num;
    __syncthreads();
    if (tg == 0)
        sqout[b * D_ + cy * 64 + c] =
            (psum[0][c] + psum[1][c] + psum[2][c] + psum[3][c]) / den;
}

// ---------------------------------------------------------------------------
// z_kernel: 256 blocks, block r computes z[b][r] for all 16 b
// ---------------------------------------------------------------------------
__global__ __launch_bounds__(256) void z_kernel(
    const float* __restrict__ q, const float* __restrict__ sq,
    const float* __restrict__ protos, const int* __restrict__ pidx,
    const float* __restrict__ Wq_w, const float* __restrict__ Wq_b,
    const float* __restrict__ Ws_w, const float* __restrict__ Ws_b,
    float* __restrict__ zout)
{
    const int r   = blockIdx.x;
    const int tid = threadIdx.x;
    const int bb  = tid >> 4;       // batch
    const int c   = tid & 15;       // 16-elem chunk
    const float4* wq = reinterpret_cast<const float4*>(Wq_w + (size_t)r * D_) + c * 4;
    const float4* ws = reinterpret_cast<const float4*>(Ws_w + (size_t)r * D_) + c * 4;
    const float4* qv = reinterpret_cast<const float4*>(q  + bb * D_) + c * 4;
    const float4* sv = reinterpret_cast<const float4*>(sq + bb * D_) + c * 4;
    float a = 0.f;
#pragma unroll
    for (int i = 0; i < 4; ++i) {
        float4 w1 = wq[i], w2 = ws[i], v1 = qv[i], v2 = sv[i];
        a += w1.x * v1.x + w1.y * v1.y + w1.z * v1.z + w1.w * v1.w;
        a += w2.x * v2.x + w2.y * v2.y + w2.z * v2.z + w2.w * v2.w;
    }
#pragma unroll
    for (int off = 1; off < 16; off <<= 1) a += __shfl_xor(a, off, 64);
    if (c == 0) {
        int pi = pidx[0];
        zout[bb * D_ + r] = protos[pi * D_ + r] + Wq_b[r] + Ws_b[r] + a;
    }
}

// ---------------------------------------------------------------------------
// final: per batch delta = z.(rpos-rneg); softplus; mean via atomicAdd
// ---------------------------------------------------------------------------
__global__ __launch_bounds__(256) void final_kernel(
    const float* __restrict__ zbuf,
    const float* __restrict__ rpos, const float* __restrict__ rneg,
    float* __restrict__ out)
{
    const int b   = blockIdx.x;
    const int tid = threadIdx.x;
    const int lane = tid & 63;
    const int wv   = tid >> 6;
    __shared__ float wsum[4];
    float v = zbuf[b * D_ + tid] * (rpos[b * D_ + tid] - rneg[b * D_ + tid]);
#pragma unroll
    for (int off = 1; off < 64; off <<= 1) v += __shfl_xor(v, off, 64);
    if (lane == 0) wsum[wv] = v;
    __syncthreads();
    if (tid == 0) {
        float delta = wsum[0] + wsum[1] + wsum[2] + wsum[3];
        float x = -delta;
        float sp = fmaxf(x, 0.f) + log1pf(__expf(-fabsf(x)));
        atomicAdd(out, sp * (1.0f / (float)B_));
    }
}

// ---------------------------------------------------------------------------
extern "C" void kernel_launch(void* const* d_in, const int* in_sizes, int n_in,
                              void* d_out, int out_size, void* d_ws, size_t ws_size,
                              hipStream_t stream) {
    const float* q       = (const float*)d_in[0];
    const float* r_pos   = (const float*)d_in[1];
    const float* r_neg   = (const float*)d_in[2];
    const float* h       = (const float*)d_in[3];
    const float* rp      = (const float*)d_in[4];
    const float* rn      = (const float*)d_in[5];
    const int*   lengths = (const int*)d_in[6];
    const int*   pidx    = (const int*)d_in[7];
    const float* protos  = (const float*)d_in[8];
    const float* Wh_w    = (const float*)d_in[9];
    const float* Wh_b    = (const float*)d_in[10];
    const float* Wq_w    = (const float*)d_in[11];
    const float* Wq_b    = (const float*)d_in[12];
    const float* Ws_w    = (const float*)d_in[13];
    const float* Ws_b    = (const float*)d_in[14];
    float* out = (float*)d_out;

    char* ws = (char*)d_ws;
    unsigned short* wsW = (unsigned short*)ws;          // 256 KB bf16 W (d-major)
    float* aeff     = (float*)(ws + 262144);            // 16 KB
    float* partials = (float*)(ws + 278528);            // 16*128*260*4 = 2,129,920 B
    int*   tiles    = (int*)(ws + 2408448);             // 8 KB
    int*   tileCnt  = (int*)(ws + 2416640);             // 4 B
    float* sqws     = (float*)ws;                       // alias wsW (dead after main)
    float* zbuf     = (float*)(ws + 16384);             // alias wsW+16KB

    hipMemsetAsync(out, 0, sizeof(float), stream);
    prep_kernel<<<dim3(273), dim3(256), 0, stream>>>(Wh_w, protos, q, pidx, lengths,
                                                     (unsigned int*)wsW, aeff, tiles, tileCnt);
    main_kernel<<<dim3(B_ * MAXT), dim3(64), 0, stream>>>(h, rp, rn, lengths, wsW, aeff, Wh_b,
                                                          partials, tiles, tileCnt);
    sq_kernel<<<dim3(B_, 4), dim3(256), 0, stream>>>(partials, lengths, sqws);
    z_kernel<<<dim3(256), dim3(256), 0, stream>>>(q, sqws, protos, pidx,
                                                  Wq_w, Wq_b, Ws_w, Ws_b, zbuf);
    final_kernel<<<dim3(B_), dim3(256), 0, stream>>>(zbuf, r_pos, r_neg, out);
}